// Round 3
// baseline (518.721 us; speedup 1.0000x reference)
//
#include <hip/hip_runtime.h>

// ---------------------------------------------------------------------------
// SumAggregation v3: layout-first rewrite.
//   prep:    weights fp32 -> bf16 in ws
//   trans:   feats (CIN,A) fp32 -> fT (A,CIN) bf16 in ws  (+ fused Z-stats MFMA)
//   finZ:    BN1 scale/shift
//   fused<2>: GEMM1(fT,bf16) -> h(LDS) -> GEMM2 -> Y-stats
//   finY:    BN2 scale/shift
//   fused<3>: recompute, normalize, *prob, scatter-store (f32x4)
//   zero_tail: inactive half of out = 0
// ws: 12KB stats + 176KB bf16 weights + 24MB fT  (~25.4MB)
// ---------------------------------------------------------------------------

#define AT    65536
#define MHALF 16384

typedef __bf16 bf16_t;
typedef bf16_t bf16x8 __attribute__((ext_vector_type(8)));
typedef bf16_t bf16x4 __attribute__((ext_vector_type(4)));
typedef float  f32x4  __attribute__((ext_vector_type(4)));

__device__ __forceinline__ f32x4 mfma16(bf16x8 a, bf16x8 b, f32x4 c) {
  return __builtin_amdgcn_mfma_f32_16x16x32_bf16(a, b, c, 0, 0, 0);
}

__device__ __forceinline__ float redcol16(float v) {
  v += __shfl_xor(v, 1, 64);
  v += __shfl_xor(v, 2, 64);
  v += __shfl_xor(v, 4, 64);
  v += __shfl_xor(v, 8, 64);
  return v;
}

// ---------------------------------------------------------------------------
__global__ __launch_bounds__(256) void prep_weights(
    const float* __restrict__ Wa0, const float* __restrict__ Wa1,
    const float* __restrict__ Wb0, const float* __restrict__ Wb1,
    bf16_t* __restrict__ Wab0, bf16_t* __restrict__ Wab1,
    bf16_t* __restrict__ Wbb0, bf16_t* __restrict__ Wbb1)
{
  const int i = threadIdx.x + blockIdx.x * 256;
  if (i >= 90112) return;
  if (i < 8192)        Wab0[i]         = (bf16_t)Wa0[i];
  else if (i < 24576)  Wab1[i - 8192]  = (bf16_t)Wa1[i - 8192];
  else if (i < 57344)  Wbb0[i - 24576] = (bf16_t)Wb0[i - 24576];
  else                 Wbb1[i - 57344] = (bf16_t)Wb1[i - 57344];
}

// ---------------------------------------------------------------------------
// Transpose one group's feats to fT (A x CIN bf16) and accumulate Z-stats.
// LDS tile [a][c] bf16, 16B-granule XOR swizzle: phys_g = g ^ (a & 7).
template <int CIN>
__global__ __launch_bounds__(256) void trans_stats(
    const float* __restrict__ feats, const bf16_t* __restrict__ Wab,
    float* __restrict__ zsum, float* __restrict__ zssq,
    bf16_t* __restrict__ fT)
{
  constexpr int KS1  = CIN / 32;
  constexpr int GR   = CIN / 8;     // 16B granules per row
  constexpr int ROWB = CIN * 2;     // LDS row bytes
  __shared__ __align__(16) char tile[64 * ROWB];

  const int tid = threadIdx.x, lane = tid & 63;
  const int lr = lane & 15, lk = lane >> 4, wid = tid >> 6;
  const int a0 = (int)blockIdx.x * 64;

  // ---- stage: coalesced fp32 loads -> bf16 transposed LDS tile
  {
    const int cbase = tid >> 4;        // 0..15
    const int aq    = (tid & 15) * 4;  // a quad base
#pragma unroll
    for (int cc = 0; cc < CIN / 16; ++cc) {
      const int c = cc * 16 + cbase;
      const f32x4 v = *reinterpret_cast<const f32x4*>(
          feats + (size_t)c * AT + a0 + aq);
      const int gsw = c >> 3, cb = (c & 7) * 2;
#pragma unroll
      for (int i = 0; i < 4; ++i) {
        const int a = aq + i;
        *reinterpret_cast<bf16_t*>(
            tile + a * ROWB + ((gsw ^ (a & 7)) << 4) + cb) = (bf16_t)v[i];
      }
    }
  }
  __syncthreads();

  // ---- write fT rows (full-line bf16x8 stores, issued early)
  {
    const int g  = tid % GR;
    const int ar = tid / GR;            // 0..(256/GR-1)
#pragma unroll
    for (int i = 0; i < 64 / (256 / GR); ++i) {
      const int a = ar + (256 / GR) * i;
      const bf16x8 v = *reinterpret_cast<const bf16x8*>(
          tile + a * ROWB + ((g ^ (a & 7)) << 4));
      *reinterpret_cast<bf16x8*>(fT + (size_t)(a0 + a) * CIN + g * 8) = v;
    }
  }

  // ---- Z-stats MFMA: col = lr + 16*nt (conflict-friendly with the swizzle)
  bf16x8 WaF[2][KS1];
#pragma unroll
  for (int mi = 0; mi < 2; ++mi) {
    const bf16_t* base = Wab + (size_t)((2 * wid + mi) * 16 + lr) * CIN + lk * 8;
#pragma unroll
    for (int ks = 0; ks < KS1; ++ks)
      WaF[mi][ks] = *reinterpret_cast<const bf16x8*>(base + ks * 32);
  }

  float zs[2][4] = {}, zq[2][4] = {};
#pragma unroll
  for (int nt = 0; nt < 4; ++nt) {
    const int col = lr + 16 * nt;
    f32x4 z0 = {0.f, 0.f, 0.f, 0.f}, z1 = {0.f, 0.f, 0.f, 0.f};
#pragma unroll
    for (int ks = 0; ks < KS1; ++ks) {
      const int g = ks * 4 + lk;
      const bf16x8 bfr = *reinterpret_cast<const bf16x8*>(
          tile + col * ROWB + ((g ^ (col & 7)) << 4));
      z0 = mfma16(WaF[0][ks], bfr, z0);
      z1 = mfma16(WaF[1][ks], bfr, z1);
    }
#pragma unroll
    for (int i = 0; i < 4; ++i) {
      zs[0][i] += z0[i]; zq[0][i] += z0[i] * z0[i];
      zs[1][i] += z1[i]; zq[1][i] += z1[i] * z1[i];
    }
  }
#pragma unroll
  for (int mi = 0; mi < 2; ++mi)
#pragma unroll
    for (int i = 0; i < 4; ++i) {
      const float s = redcol16(zs[mi][i]);
      const float q = redcol16(zq[mi][i]);
      if (lr == 0) {
        const int ch = (2 * wid + mi) * 16 + lk * 4 + i;
        atomicAdd(&zsum[ch], s);
        atomicAdd(&zssq[ch], q);
      }
    }
}

// ---------------------------------------------------------------------------
// GEMM1 for one group: Z = Wab @ fT^T, bn1+relu -> hbuf (swizzled, 16KB).
template <int CIN>
__device__ __forceinline__ void gemm1g(
    const bf16_t* __restrict__ fT, const bf16_t* __restrict__ Wab,
    const float* __restrict__ scaleZ, const float* __restrict__ shiftZ,
    char* __restrict__ hbuf, int a0, int tid)
{
  constexpr int KS1 = CIN / 32;
  const int wid = tid >> 6, lane = tid & 63, lr = lane & 15, lk = lane >> 4;

  bf16x8 WaF[2][KS1];
#pragma unroll
  for (int mi = 0; mi < 2; ++mi) {
    const bf16_t* base = Wab + (size_t)((2 * wid + mi) * 16 + lr) * CIN + lk * 8;
#pragma unroll
    for (int ks = 0; ks < KS1; ++ks)
      WaF[mi][ks] = *reinterpret_cast<const bf16x8*>(base + ks * 32);
  }
  float sZ[2][4], bZ[2][4];
#pragma unroll
  for (int mi = 0; mi < 2; ++mi)
#pragma unroll
    for (int i = 0; i < 4; ++i) {
      const int ch = (2 * wid + mi) * 16 + lk * 4 + i;
      sZ[mi][i] = scaleZ[ch]; bZ[mi][i] = shiftZ[ch];
    }

#pragma unroll
  for (int nt = 0; nt < 4; ++nt) {
    const int col = a0 + lr * 4 + nt;
    const bf16_t* fb = fT + (size_t)col * CIN + lk * 8;
    f32x4 z[2];
    z[0] = f32x4{0.f, 0.f, 0.f, 0.f};
    z[1] = f32x4{0.f, 0.f, 0.f, 0.f};
#pragma unroll
    for (int ks = 0; ks < KS1; ++ks) {
      const bf16x8 bfr = *reinterpret_cast<const bf16x8*>(fb + ks * 32);
      z[0] = mfma16(WaF[0][ks], bfr, z[0]);
      z[1] = mfma16(WaF[1][ks], bfr, z[1]);
    }
#pragma unroll
    for (int mi = 0; mi < 2; ++mi) {
      bf16x4 hv;
#pragma unroll
      for (int i = 0; i < 4; ++i)
        hv[i] = (bf16_t)fmaxf(z[mi][i] * sZ[mi][i] + bZ[mi][i], 0.f);
      const int chunk = (2 * wid + mi) * 2 + (lk >> 1);
      const int addr = nt * 4096 + lr * 256 + ((chunk ^ (lr & 7)) << 4) + ((lk & 1) << 3);
      *reinterpret_cast<bf16x4*>(hbuf + addr) = hv;
    }
  }
}

// ---------------------------------------------------------------------------
// GEMM2 half-pass for one group (COUT rows [half*128, half*128+128)).
template <int PHASE>
__device__ __forceinline__ void gemm2g(
    const char* __restrict__ hbuf, const bf16_t* __restrict__ Wbb,
    const float* __restrict__ prob,
    float* __restrict__ ysum, float* __restrict__ yssq,
    const float* __restrict__ scaleY, const float* __restrict__ shiftY,
    int half, int a0, int tid, float (&oval)[4][2][4])
{
  const int wid = tid >> 6, lane = tid & 63, lr = lane & 15, lk = lane >> 4;

  bf16x8 WbF[2][4];
#pragma unroll
  for (int mi = 0; mi < 2; ++mi) {
    const bf16_t* base =
        Wbb + (size_t)(half * 128 + (2 * wid + mi) * 16 + lr) * 128 + lk * 8;
#pragma unroll
    for (int ks = 0; ks < 4; ++ks)
      WbF[mi][ks] = *reinterpret_cast<const bf16x8*>(base + ks * 32);
  }

  float sY[2][4], bY[2][4];
  f32x4 p4;
  if constexpr (PHASE == 3) {
#pragma unroll
    for (int mi = 0; mi < 2; ++mi)
#pragma unroll
      for (int i = 0; i < 4; ++i) {
        const int ch = half * 128 + (2 * wid + mi) * 16 + lk * 4 + i;
        sY[mi][i] = scaleY[ch]; bY[mi][i] = shiftY[ch];
      }
    const int col0 = a0 + lr * 4;
    p4 = *reinterpret_cast<const f32x4*>(
        prob + (((size_t)(col0 >> 14)) << 15) + (col0 & (MHALF - 1)));
  }

  float ys[2][4] = {}, yq[2][4] = {};
#pragma unroll
  for (int nt = 0; nt < 4; ++nt) {
    f32x4 yacc[2];
    yacc[0] = f32x4{0.f, 0.f, 0.f, 0.f};
    yacc[1] = f32x4{0.f, 0.f, 0.f, 0.f};
#pragma unroll
    for (int ks = 0; ks < 4; ++ks) {
      const int chunk = ks * 4 + lk;
      const bf16x8 hf = *reinterpret_cast<const bf16x8*>(
          hbuf + nt * 4096 + lr * 256 + ((chunk ^ (lr & 7)) << 4));
      yacc[0] = mfma16(WbF[0][ks], hf, yacc[0]);
      yacc[1] = mfma16(WbF[1][ks], hf, yacc[1]);
    }
    if constexpr (PHASE == 2) {
#pragma unroll
      for (int mi = 0; mi < 2; ++mi)
#pragma unroll
        for (int i = 0; i < 4; ++i) {
          const float y = yacc[mi][i];
          ys[mi][i] += y; yq[mi][i] += y * y;
        }
    } else {
#pragma unroll
      for (int mi = 0; mi < 2; ++mi)
#pragma unroll
        for (int i = 0; i < 4; ++i)
          oval[nt][mi][i] += fmaxf(yacc[mi][i] * sY[mi][i] + bY[mi][i], 0.f) * p4[nt];
    }
  }

  if constexpr (PHASE == 2) {
#pragma unroll
    for (int mi = 0; mi < 2; ++mi)
#pragma unroll
      for (int i = 0; i < 4; ++i) {
        const float s = redcol16(ys[mi][i]);
        const float q = redcol16(yq[mi][i]);
        if (lr == 0) {
          const int ch = half * 128 + (2 * wid + mi) * 16 + lk * 4 + i;
          atomicAdd(&ysum[ch], s);
          atomicAdd(&yssq[ch], q);
        }
      }
  }
}

// ---------------------------------------------------------------------------
template <int PHASE>
__global__ __launch_bounds__(256, 4) void fused_all(
    const bf16_t* __restrict__ fT0, const bf16_t* __restrict__ fT1,
    const bf16_t* __restrict__ Wab0, const bf16_t* __restrict__ Wab1,
    const bf16_t* __restrict__ Wbb0, const bf16_t* __restrict__ Wbb1,
    const float* __restrict__ prob0, const float* __restrict__ prob1,
    const float* __restrict__ scaleZ, const float* __restrict__ shiftZ,
    float* __restrict__ ysum, float* __restrict__ yssq,
    const float* __restrict__ scaleY, const float* __restrict__ shiftY,
    float* __restrict__ out)
{
  __shared__ __align__(16) char hbuf[2][16384];
  const int tid = threadIdx.x;
  const int a0 = (int)blockIdx.x * 64;

  gemm1g<64>(fT0, Wab0, scaleZ, shiftZ, hbuf[0], a0, tid);
  gemm1g<128>(fT1, Wab1, scaleZ + 128, shiftZ + 128, hbuf[1], a0, tid);
  __syncthreads();

  const int lane = tid & 63, lr = lane & 15, lkk = lane >> 4, wid = tid >> 6;

#pragma unroll
  for (int half = 0; half < 2; ++half) {
    float oval[4][2][4];
#pragma unroll
    for (int nt = 0; nt < 4; ++nt)
#pragma unroll
      for (int mi = 0; mi < 2; ++mi)
#pragma unroll
        for (int i = 0; i < 4; ++i) oval[nt][mi][i] = 0.f;

    gemm2g<PHASE>(hbuf[0], Wbb0, prob0, ysum, yssq,
                  scaleY, shiftY, half, a0, tid, oval);
    gemm2g<PHASE>(hbuf[1], Wbb1, prob1, ysum + 256, yssq + 256,
                  scaleY + 256, shiftY + 256, half, a0, tid, oval);

    if constexpr (PHASE == 3) {
      const int col0 = a0 + lr * 4;
      const int b = col0 >> 14, m0 = col0 & (MHALF - 1);
#pragma unroll
      for (int mi = 0; mi < 2; ++mi)
#pragma unroll
        for (int i = 0; i < 4; ++i) {
          const int ch = half * 128 + wid * 32 + mi * 16 + lkk * 4 + i;
          f32x4 w;
#pragma unroll
          for (int nt = 0; nt < 4; ++nt) w[nt] = oval[nt][mi][i];
          *reinterpret_cast<f32x4*>(
              out + (((size_t)(b * 256 + ch)) << 15) + m0) = w;
        }
    }
  }
}

// ---------------------------------------------------------------------------
__global__ void finalize_stats(const float* __restrict__ sum,
                               const float* __restrict__ ssq,
                               const float* __restrict__ gamma0,
                               const float* __restrict__ beta0,
                               const float* __restrict__ gamma1,
                               const float* __restrict__ beta1,
                               float* __restrict__ scale,
                               float* __restrict__ shift, int nch)
{
  const int t = threadIdx.x;             // 2*nch threads
  const int g = t / nch;
  const int c = t - g * nch;
  const float inv = 1.f / 65536.f;       // 1/A
  const float mu  = sum[t] * inv;
  const float var = ssq[t] * inv - mu * mu;  // biased variance
  const float ga  = (g ? gamma1 : gamma0)[c];
  const float be  = (g ? beta1 : beta0)[c];
  const float sc  = ga * rsqrtf(var + 1e-5f);
  scale[t] = sc;
  shift[t] = be - mu * sc;
}

__global__ void zero_stats(float* __restrict__ ws) {
  const int t = threadIdx.x + blockIdx.x * blockDim.x;
  if (t < 1536) ws[t] = 0.f;
}

__global__ void zero_tail(float* __restrict__ out) {
  const unsigned total = 1024u * 4096u;  // (B*COUT) rows x 4096 float4
  for (unsigned i = threadIdx.x + blockIdx.x * blockDim.x; i < total;
       i += gridDim.x * blockDim.x) {
    const unsigned bc = i >> 12, r = i & 4095u;
    reinterpret_cast<float4*>(out)[(size_t)bc * 8192 + 4096 + r] =
        make_float4(0.f, 0.f, 0.f, 0.f);
  }
}

// ---------------------------------------------------------------------------
extern "C" void kernel_launch(void* const* d_in, const int* in_sizes, int n_in,
                              void* d_out, int out_size, void* d_ws, size_t ws_size,
                              hipStream_t stream)
{
  (void)in_sizes; (void)n_in; (void)out_size; (void)ws_size;
  const float* feats0 = (const float*)d_in[0];
  const float* feats1 = (const float*)d_in[1];
  const float* prob0  = (const float*)d_in[2];
  const float* prob1  = (const float*)d_in[3];
  const float* Wa0 = (const float*)d_in[6];
  const float* ga0 = (const float*)d_in[7];
  const float* ba0 = (const float*)d_in[8];
  const float* Wb0 = (const float*)d_in[9];
  const float* gb0 = (const float*)d_in[10];
  const float* bb0 = (const float*)d_in[11];
  const float* Wa1 = (const float*)d_in[12];
  const float* ga1 = (const float*)d_in[13];
  const float* ba1 = (const float*)d_in[14];
  const float* Wb1 = (const float*)d_in[15];
  const float* gb1 = (const float*)d_in[16];
  const float* bb1 = (const float*)d_in[17];

  float* out = (float*)d_out;
  float* ws  = (float*)d_ws;

  float* zsum   = ws;          // [2][128]
  float* zssq   = ws + 256;    // [2][128]
  float* ysum   = ws + 512;    // [2][256]
  float* yssq   = ws + 1024;   // [2][256]
  float* scaleZ = ws + 1536;   // [2][128]
  float* shiftZ = ws + 1792;   // [2][128]
  float* scaleY = ws + 2048;   // [2][256]
  float* shiftY = ws + 2560;   // [2][256]  -> 3072 floats = 12KB

  char* wsb = (char*)d_ws;
  bf16_t* Wab0 = (bf16_t*)(wsb + (12  << 10));   // 128x64
  bf16_t* Wab1 = (bf16_t*)(wsb + (28  << 10));   // 128x128
  bf16_t* Wbb0 = (bf16_t*)(wsb + (60  << 10));   // 256x128
  bf16_t* Wbb1 = (bf16_t*)(wsb + (124 << 10));   // 256x128
  bf16_t* fT0  = (bf16_t*)(wsb + (192 << 10));            // 65536x64
  bf16_t* fT1  = (bf16_t*)(wsb + (192 << 10) + (8 << 20)); // 65536x128

  zero_stats<<<6, 256, 0, stream>>>(ws);
  prep_weights<<<352, 256, 0, stream>>>(Wa0, Wa1, Wb0, Wb1,
                                        Wab0, Wab1, Wbb0, Wbb1);
  zero_tail<<<2048, 256, 0, stream>>>(out);

  trans_stats<64><<<1024, 256, 0, stream>>>(feats0, Wab0, zsum, zssq, fT0);
  trans_stats<128><<<1024, 256, 0, stream>>>(feats1, Wab1, zsum + 128, zssq + 128, fT1);
  finalize_stats<<<1, 256, 0, stream>>>(zsum, zssq, ga0, ba0, ga1, ba1,
                                        scaleZ, shiftZ, 128);

  fused_all<2><<<1024, 256, 0, stream>>>(fT0, fT1, Wab0, Wab1, Wbb0, Wbb1,
      prob0, prob1, scaleZ, shiftZ, ysum, yssq, scaleY, shiftY, out);
  finalize_stats<<<1, 512, 0, stream>>>(ysum, yssq, gb0, bb0, gb1, bb1,
                                        scaleY, shiftY, 256);

  fused_all<3><<<1024, 256, 0, stream>>>(fT0, fT1, Wab0, Wab1, Wbb0, Wbb1,
      prob0, prob1, scaleZ, shiftZ, ysum, yssq, scaleY, shiftY, out);
}

// Round 4
// 168.646 us; speedup vs baseline: 3.0758x; 3.0758x over previous
//
#include <hip/hip_runtime.h>

// ---------------------------------------------------------------------------
// SumAggregation v4: latency-first restructure.
//  prep:        weights fp32->bf16 (ws)
//  trans<CIN>:  feats (CIN,A) -> fT (A,CIN) bf16 + Z-stat block partials
//  reduce_fin:  partials -> BN scale/shift              (x2 for Z)
//  fused<2>:    GEMM1->h(wave-private LDS)->GEMM2 -> Y-stat block partials
//  reduce_fin:  partials -> BN2 scale/shift             (x2 for Y)
//  fused<3>:    recompute, bn, *prob, store out (+ fused zero tail)
//
// Key points: no __launch_bounds__ occupancy clamp (VGPR headroom for MLP),
// wave-private 32-col tiles (no barriers in main path), batched independent
// loads, no global atomics (block partials + tiny reduce kernels).
// ---------------------------------------------------------------------------

#define AT 65536

typedef __bf16 bf16_t;
typedef bf16_t bf16x8 __attribute__((ext_vector_type(8)));
typedef bf16_t bf16x4 __attribute__((ext_vector_type(4)));
typedef float  f32x4  __attribute__((ext_vector_type(4)));

__device__ __forceinline__ f32x4 mfma16(bf16x8 a, bf16x8 b, f32x4 c) {
  return __builtin_amdgcn_mfma_f32_16x16x32_bf16(a, b, c, 0, 0, 0);
}

__device__ __forceinline__ float redcol16(float v) {
  v += __shfl_xor(v, 1, 64);
  v += __shfl_xor(v, 2, 64);
  v += __shfl_xor(v, 4, 64);
  v += __shfl_xor(v, 8, 64);
  return v;
}

// ---------------------------------------------------------------------------
__global__ __launch_bounds__(256) void prep_weights(
    const float* __restrict__ Wa0, const float* __restrict__ Wa1,
    const float* __restrict__ Wb0, const float* __restrict__ Wb1,
    bf16_t* __restrict__ Wab0, bf16_t* __restrict__ Wab1,
    bf16_t* __restrict__ Wbb0, bf16_t* __restrict__ Wbb1)
{
  const int i = threadIdx.x + blockIdx.x * 256;
  if (i >= 90112) return;
  if (i < 8192)        Wab0[i]         = (bf16_t)Wa0[i];
  else if (i < 24576)  Wab1[i - 8192]  = (bf16_t)Wa1[i - 8192];
  else if (i < 57344)  Wbb0[i - 24576] = (bf16_t)Wb0[i - 24576];
  else                 Wbb1[i - 57344] = (bf16_t)Wb1[i - 57344];
}

// ---------------------------------------------------------------------------
// Transpose feats -> fT (A x CIN bf16), fused Z-stats -> per-block partials.
// Partial layout per block: [s(0..127), q(0..127)].
template <int CIN>
__global__ __launch_bounds__(256) void trans_stats(
    const float* __restrict__ feats, const bf16_t* __restrict__ Wab,
    float* __restrict__ Zpart, bf16_t* __restrict__ fT)
{
  constexpr int KS1  = CIN / 32;
  constexpr int GR   = CIN / 8;     // 16B granules per row
  constexpr int ROWB = CIN * 2;     // LDS row bytes
  __shared__ __align__(16) char tile[64 * ROWB];

  const int tid = threadIdx.x, lane = tid & 63;
  const int lr = lane & 15, lk = lane >> 4, wid = tid >> 6;
  const int a0 = (int)blockIdx.x * 64;

  // ---- batch-load feats (all loads issued before any use)
  f32x4 v[CIN / 16];
  const int cb = tid >> 4, aq = (tid & 15) * 4;
#pragma unroll
  for (int cc = 0; cc < CIN / 16; ++cc)
    v[cc] = *reinterpret_cast<const f32x4*>(
        feats + (size_t)(cc * 16 + cb) * AT + a0 + aq);

  // ---- convert + transposed LDS writes (16B-granule XOR swizzle)
#pragma unroll
  for (int cc = 0; cc < CIN / 16; ++cc) {
    const int c = cc * 16 + cb;
    const int gsw = c >> 3, cbyte = (c & 7) * 2;
#pragma unroll
    for (int i = 0; i < 4; ++i) {
      const int a = aq + i;
      *reinterpret_cast<bf16_t*>(
          tile + a * ROWB + ((gsw ^ (a & 7)) << 4) + cbyte) = (bf16_t)v[cc][i];
    }
  }
  __syncthreads();

  // ---- write fT rows (bf16x8 full-line stores)
  {
    const int g = tid % GR, ar = tid / GR;
#pragma unroll
    for (int i = 0; i < (GR * 64) / 256; ++i) {
      const int a = ar + (256 / GR) * i;
      const bf16x8 w = *reinterpret_cast<const bf16x8*>(
          tile + a * ROWB + ((g ^ (a & 7)) << 4));
      *reinterpret_cast<bf16x8*>(fT + (size_t)(a0 + a) * CIN + g * 8) = w;
    }
  }

  // ---- Z-stats via MFMA on the LDS tile
  bf16x8 WaF[2][KS1];
#pragma unroll
  for (int mi = 0; mi < 2; ++mi) {
    const bf16_t* base = Wab + (size_t)((2 * wid + mi) * 16 + lr) * CIN + lk * 8;
#pragma unroll
    for (int ks = 0; ks < KS1; ++ks)
      WaF[mi][ks] = *reinterpret_cast<const bf16x8*>(base + ks * 32);
  }

  float zs[2][4] = {}, zq[2][4] = {};
#pragma unroll
  for (int nt = 0; nt < 4; ++nt) {
    const int col = lr + 16 * nt;
    f32x4 z0 = {0.f, 0.f, 0.f, 0.f}, z1 = {0.f, 0.f, 0.f, 0.f};
#pragma unroll
    for (int ks = 0; ks < KS1; ++ks) {
      const int g = ks * 4 + lk;
      const bf16x8 bfr = *reinterpret_cast<const bf16x8*>(
          tile + col * ROWB + ((g ^ (col & 7)) << 4));
      z0 = mfma16(WaF[0][ks], bfr, z0);
      z1 = mfma16(WaF[1][ks], bfr, z1);
    }
#pragma unroll
    for (int i = 0; i < 4; ++i) {
      zs[0][i] += z0[i]; zq[0][i] += z0[i] * z0[i];
      zs[1][i] += z1[i]; zq[1][i] += z1[i] * z1[i];
    }
  }
#pragma unroll
  for (int mi = 0; mi < 2; ++mi) {
#pragma unroll
    for (int i = 0; i < 4; ++i) {
      zs[mi][i] = redcol16(zs[mi][i]);
      zq[mi][i] = redcol16(zq[mi][i]);
    }
    float vs = zs[mi][0], vq = zq[mi][0];
    vs = ((lr & 3) == 1) ? zs[mi][1] : vs;  vq = ((lr & 3) == 1) ? zq[mi][1] : vq;
    vs = ((lr & 3) == 2) ? zs[mi][2] : vs;  vq = ((lr & 3) == 2) ? zq[mi][2] : vq;
    vs = ((lr & 3) == 3) ? zs[mi][3] : vs;  vq = ((lr & 3) == 3) ? zq[mi][3] : vq;
    const float vv = (lr & 4) ? vq : vs;
    if (lr < 8)
      Zpart[(size_t)blockIdx.x * 256 + (lr >> 2) * 128 +
            (2 * wid + mi) * 16 + lk * 4 + (lr & 3)] = vv;
  }
}

// ---------------------------------------------------------------------------
// Per-channel partial reduction -> BN scale/shift.
// part layout per source block: [s(0..nch-1), q(0..nch-1)], row stride `stride`.
__global__ void reduce_fin(const float* __restrict__ part, int nblk, int stride,
                           int nch, const float* __restrict__ gamma,
                           const float* __restrict__ beta,
                           float* __restrict__ scale, float* __restrict__ shift)
{
  const int c = blockIdx.x;        // one block per channel
  const int t = threadIdx.x;       // 64 threads
  float s = 0.f, q = 0.f;
  for (int b = t; b < nblk; b += 64) {
    s += part[(size_t)b * stride + c];
    q += part[(size_t)b * stride + nch + c];
  }
#pragma unroll
  for (int o = 1; o < 64; o <<= 1) {
    s += __shfl_xor(s, o, 64);
    q += __shfl_xor(q, o, 64);
  }
  if (t == 0) {
    const float inv = 1.f / 65536.f;
    const float mu  = s * inv;
    const float var = q * inv - mu * mu;
    const float sc  = gamma[c] * rsqrtf(var + 1e-5f);
    scale[c] = sc;
    shift[c] = beta[c] - mu * sc;
  }
}

// ---------------------------------------------------------------------------
// GEMM1 for one group, wave-private: 32 cols, all 128 h-channels -> hw (LDS).
template <int CIN>
__device__ __forceinline__ void gemm1_dev(
    const bf16_t* __restrict__ fT, const bf16_t* __restrict__ Wab,
    const float* __restrict__ scZ, const float* __restrict__ shZ,
    char* __restrict__ hw, int colbase, int lr, int lk)
{
  constexpr int KS = CIN / 32;

  // B-fragments for my 32 cols: all issued up front
  bf16x8 bf[2][KS];
#pragma unroll
  for (int sub = 0; sub < 2; ++sub)
#pragma unroll
    for (int ks = 0; ks < KS; ++ks)
      bf[sub][ks] = *reinterpret_cast<const bf16x8*>(
          fT + (size_t)(colbase + sub * 16 + lr) * CIN + lk * 8 + ks * 32);

#pragma unroll 2
  for (int rb = 0; rb < 8; ++rb) {
    bf16x8 af[KS];
    const bf16_t* wa = Wab + (size_t)(rb * 16 + lr) * CIN + lk * 8;
#pragma unroll
    for (int ks = 0; ks < KS; ++ks)
      af[ks] = *reinterpret_cast<const bf16x8*>(wa + ks * 32);

    f32x4 acc[2];
    acc[0] = f32x4{0.f, 0.f, 0.f, 0.f};
    acc[1] = f32x4{0.f, 0.f, 0.f, 0.f};
#pragma unroll
    for (int ks = 0; ks < KS; ++ks) {
      acc[0] = mfma16(af[ks], bf[0][ks], acc[0]);
      acc[1] = mfma16(af[ks], bf[1][ks], acc[1]);
    }

    const f32x4 sv = *reinterpret_cast<const f32x4*>(scZ + rb * 16 + lk * 4);
    const f32x4 bv = *reinterpret_cast<const f32x4*>(shZ + rb * 16 + lk * 4);
#pragma unroll
    for (int sub = 0; sub < 2; ++sub) {
      bf16x4 hv;
#pragma unroll
      for (int i = 0; i < 4; ++i)
        hv[i] = (bf16_t)fmaxf(acc[sub][i] * sv[i] + bv[i], 0.f);
      const int col = sub * 16 + lr;                 // wave-local col 0..31
      const int g8  = rb * 2 + (lk >> 1);            // 16B granule of ch-range
      *reinterpret_cast<bf16x4*>(
          hw + col * 256 + ((g8 ^ (col & 7)) << 4) + ((lk & 1) << 3)) = hv;
    }
  }
}

// ---------------------------------------------------------------------------
// PHASE 2: Y-stats -> per-block partials [g][sq][256].
// PHASE 3: out = relu(bn(Y0))*p0 + relu(bn(Y1))*p1, + zero tail.
template <int PHASE>
__global__ __launch_bounds__(256) void fused_pass(
    const bf16_t* __restrict__ fT0, const bf16_t* __restrict__ fT1,
    const bf16_t* __restrict__ Wab0, const bf16_t* __restrict__ Wab1,
    const bf16_t* __restrict__ Wbb0, const bf16_t* __restrict__ Wbb1,
    const float* __restrict__ prob0, const float* __restrict__ prob1,
    const float* __restrict__ scaleZ, const float* __restrict__ shiftZ,
    const float* __restrict__ scaleY, const float* __restrict__ shiftY,
    float* __restrict__ Ypart, float* __restrict__ out)
{
  __shared__ __align__(16) char hbuf[4][2][8192];  // [wave][group][32col*256B]
  __shared__ float sstat[(PHASE == 2) ? 1024 : 4]; // [g][sq][256] (PHASE2)

  const int tid = threadIdx.x, wid = tid >> 6, lane = tid & 63;
  const int lr = lane & 15, lk = lane >> 4;
  const int colbase = (int)blockIdx.x * 128 + wid * 32;

  if constexpr (PHASE == 2) {
    sstat[tid] = 0.f; sstat[tid + 256] = 0.f;
    sstat[tid + 512] = 0.f; sstat[tid + 768] = 0.f;
  }

  // ---- GEMM1 both groups (wave-private h)
  gemm1_dev<64>(fT0, Wab0, scaleZ, shiftZ, &hbuf[wid][0][0], colbase, lr, lk);
  gemm1_dev<128>(fT1, Wab1, scaleZ + 128, shiftZ + 128, &hbuf[wid][1][0],
                 colbase, lr, lk);

  if constexpr (PHASE == 2) __syncthreads();  // sstat zeros visible

  // ---- prob values (PHASE 3)
  float p0v[2] = {0.f, 0.f}, p1v[2] = {0.f, 0.f};
  const int bC = (colbase >> 14) * 256;
  const int m0 = colbase & 16383;
  if constexpr (PHASE == 3) {
    const int b = colbase >> 14;
#pragma unroll
    for (int sub = 0; sub < 2; ++sub) {
      const int mm = m0 + sub * 16 + lr;
      p0v[sub] = prob0[((size_t)b << 15) + mm];
      p1v[sub] = prob1[((size_t)b << 15) + mm];
    }
  }

  // ---- GEMM2: both groups, 16 row-blocks of 16 channels
#pragma unroll 2
  for (int rb2 = 0; rb2 < 16; ++rb2) {
    bf16x8 a0f[4], a1f[4];
    const bf16_t* w0 = Wbb0 + (size_t)(rb2 * 16 + lr) * 128 + lk * 8;
    const bf16_t* w1 = Wbb1 + (size_t)(rb2 * 16 + lr) * 128 + lk * 8;
#pragma unroll
    for (int ks = 0; ks < 4; ++ks) {
      a0f[ks] = *reinterpret_cast<const bf16x8*>(w0 + ks * 32);
      a1f[ks] = *reinterpret_cast<const bf16x8*>(w1 + ks * 32);
    }

    f32x4 acc0[2], acc1[2];
    acc0[0] = f32x4{0.f, 0.f, 0.f, 0.f}; acc0[1] = f32x4{0.f, 0.f, 0.f, 0.f};
    acc1[0] = f32x4{0.f, 0.f, 0.f, 0.f}; acc1[1] = f32x4{0.f, 0.f, 0.f, 0.f};
#pragma unroll
    for (int ks2 = 0; ks2 < 4; ++ks2) {
#pragma unroll
      for (int sub = 0; sub < 2; ++sub) {
        const int col = sub * 16 + lr;
        const int off = col * 256 + (((ks2 * 4 + lk) ^ (col & 7)) << 4);
        const bf16x8 h0 = *reinterpret_cast<const bf16x8*>(&hbuf[wid][0][0] + off);
        acc0[sub] = mfma16(a0f[ks2], h0, acc0[sub]);
        const bf16x8 h1 = *reinterpret_cast<const bf16x8*>(&hbuf[wid][1][0] + off);
        acc1[sub] = mfma16(a1f[ks2], h1, acc1[sub]);
      }
    }

    if constexpr (PHASE == 2) {
#pragma unroll
      for (int g = 0; g < 2; ++g) {
        const f32x4* ac = g ? acc1 : acc0;
        float s[4], q[4];
#pragma unroll
        for (int i = 0; i < 4; ++i) {
          s[i] = redcol16(ac[0][i] + ac[1][i]);
          q[i] = redcol16(ac[0][i] * ac[0][i] + ac[1][i] * ac[1][i]);
        }
        float vs = s[0], vq = q[0];
        vs = ((lr & 3) == 1) ? s[1] : vs;  vq = ((lr & 3) == 1) ? q[1] : vq;
        vs = ((lr & 3) == 2) ? s[2] : vs;  vq = ((lr & 3) == 2) ? q[2] : vq;
        vs = ((lr & 3) == 3) ? s[3] : vs;  vq = ((lr & 3) == 3) ? q[3] : vq;
        const float vv = (lr & 4) ? vq : vs;
        if (lr < 8)
          atomicAdd(&sstat[g * 512 + ((lr >> 2) << 8) +
                           rb2 * 16 + lk * 4 + (lr & 3)], vv);
      }
    } else {
      const f32x4 sv0 = *reinterpret_cast<const f32x4*>(scaleY + rb2 * 16 + lk * 4);
      const f32x4 bv0 = *reinterpret_cast<const f32x4*>(shiftY + rb2 * 16 + lk * 4);
      const f32x4 sv1 = *reinterpret_cast<const f32x4*>(scaleY + 256 + rb2 * 16 + lk * 4);
      const f32x4 bv1 = *reinterpret_cast<const f32x4*>(shiftY + 256 + rb2 * 16 + lk * 4);
#pragma unroll
      for (int sub = 0; sub < 2; ++sub) {
        const int mm = m0 + sub * 16 + lr;
#pragma unroll
        for (int i = 0; i < 4; ++i) {
          const int ch = rb2 * 16 + lk * 4 + i;
          const float v =
              fmaxf(acc0[sub][i] * sv0[i] + bv0[i], 0.f) * p0v[sub] +
              fmaxf(acc1[sub][i] * sv1[i] + bv1[i], 0.f) * p1v[sub];
          float* op = out + (((size_t)(bC + ch)) << 15) + mm;
          op[0] = v;
          op[16384] = 0.f;   // fused zero tail
        }
      }
    }
  }

  if constexpr (PHASE == 2) {
    __syncthreads();
#pragma unroll
    for (int j = 0; j < 4; ++j)
      Ypart[(size_t)blockIdx.x * 1024 + j * 256 + tid] = sstat[j * 256 + tid];
  }
}

// ---------------------------------------------------------------------------
extern "C" void kernel_launch(void* const* d_in, const int* in_sizes, int n_in,
                              void* d_out, int out_size, void* d_ws, size_t ws_size,
                              hipStream_t stream)
{
  (void)in_sizes; (void)n_in; (void)out_size; (void)ws_size;
  const float* feats0 = (const float*)d_in[0];
  const float* feats1 = (const float*)d_in[1];
  const float* prob0  = (const float*)d_in[2];
  const float* prob1  = (const float*)d_in[3];
  const float* Wa0 = (const float*)d_in[6];
  const float* ga0 = (const float*)d_in[7];
  const float* ba0 = (const float*)d_in[8];
  const float* Wb0 = (const float*)d_in[9];
  const float* gb0 = (const float*)d_in[10];
  const float* bb0 = (const float*)d_in[11];
  const float* Wa1 = (const float*)d_in[12];
  const float* ga1 = (const float*)d_in[13];
  const float* ba1 = (const float*)d_in[14];
  const float* Wb1 = (const float*)d_in[15];
  const float* gb1 = (const float*)d_in[16];
  const float* bb1 = (const float*)d_in[17];

  float* out = (float*)d_out;
  char*  wsb = (char*)d_ws;

  // ws layout
  float* scaleZ = (float*)wsb;                 // [256]
  float* shiftZ = scaleZ + 256;                // [256]
  float* scaleY = shiftZ + 256;                // [512]
  float* shiftY = scaleY + 512;                // [512]  (ends at 6KB)
  bf16_t* Wab0 = (bf16_t*)(wsb + (8   << 10)); // 128x64
  bf16_t* Wab1 = (bf16_t*)(wsb + (24  << 10)); // 128x128
  bf16_t* Wbb0 = (bf16_t*)(wsb + (56  << 10)); // 256x128
  bf16_t* Wbb1 = (bf16_t*)(wsb + (120 << 10)); // 256x128
  float* ZpartG0 = (float*)(wsb + (192 << 10));            // [1024][256] 1MB
  float* ZpartG1 = (float*)(wsb + (192 << 10) + (1 << 20)); // [1024][256] 1MB
  float* Ypart   = ZpartG0;                                 // [512][1024] 2MB (aliased, disjoint lifetime)
  bf16_t* fT0 = (bf16_t*)(wsb + (2304 << 10));              // 65536x64  (8MB)
  bf16_t* fT1 = (bf16_t*)(wsb + (2304 << 10) + (8 << 20));  // 65536x128 (16MB)

  prep_weights<<<352, 256, 0, stream>>>(Wa0, Wa1, Wb0, Wb1,
                                        Wab0, Wab1, Wbb0, Wbb1);

  trans_stats<64><<<1024, 256, 0, stream>>>(feats0, Wab0, ZpartG0, fT0);
  trans_stats<128><<<1024, 256, 0, stream>>>(feats1, Wab1, ZpartG1, fT1);

  reduce_fin<<<128, 64, 0, stream>>>(ZpartG0, 1024, 256, 128, ga0, ba0,
                                     scaleZ, shiftZ);
  reduce_fin<<<128, 64, 0, stream>>>(ZpartG1, 1024, 256, 128, ga1, ba1,
                                     scaleZ + 128, shiftZ + 128);

  fused_pass<2><<<512, 256, 0, stream>>>(fT0, fT1, Wab0, Wab1, Wbb0, Wbb1,
      prob0, prob1, scaleZ, shiftZ, scaleY, shiftY, Ypart, out);

  reduce_fin<<<256, 64, 0, stream>>>(Ypart, 512, 1024, 256, gb0, bb0,
                                     scaleY, shiftY);
  reduce_fin<<<256, 64, 0, stream>>>(Ypart + 512, 512, 1024, 256, gb1, bb1,
                                     scaleY + 256, shiftY + 256);

  fused_pass<3><<<512, 256, 0, stream>>>(fT0, fT1, Wab0, Wab1, Wbb0, Wbb1,
      prob0, prob1, scaleZ, shiftZ, scaleY, shiftY, Ypart, out);
}